// Round 1
// baseline (507.695 us; speedup 1.0000x reference)
//
#include <hip/hip_runtime.h>
#include <hip/hip_bf16.h>
#include <type_traits>

// GTMGC block: B=256, N=128, D=256, H=8, hd=32, FFN=1024
// out = [X (B*N*D f32) | attn (B*H*N*N f32)]

typedef __bf16 bf16x8 __attribute__((ext_vector_type(8)));
typedef float f32x4 __attribute__((ext_vector_type(4)));

__device__ __forceinline__ float gelu_tanh(float x) {
    // jax.nn.gelu approximate=True
    float x3 = x * x * x;
    float t = tanhf(0.7978845608028654f * (x + 0.044715f * x3));
    return 0.5f * x * (1.0f + t);
}

// ---------------- weight prep: transpose to [N][K] bf16, concat qkv bias ----
__global__ __launch_bounds__(256) void prep_kernel(
    const float* __restrict__ Wq, const float* __restrict__ Wk,
    const float* __restrict__ Wv, const float* __restrict__ Wo,
    const float* __restrict__ W1, const float* __restrict__ W2,
    const float* __restrict__ bq, const float* __restrict__ bk,
    const float* __restrict__ bv,
    __bf16* __restrict__ WqkvT, __bf16* __restrict__ WoT,
    __bf16* __restrict__ W1T, __bf16* __restrict__ W2T,
    float* __restrict__ bqkv)
{
    int id = blockIdx.x * 256 + threadIdx.x;
    if (id < 196608) {                      // WqkvT: 768 x 256
        int n = id >> 8, k = id & 255;
        float v = (n < 256) ? Wq[k * 256 + n]
                : (n < 512) ? Wk[k * 256 + (n - 256)]
                            : Wv[k * 256 + (n - 512)];
        WqkvT[n * 256 + k] = (__bf16)v;
    } else if (id < 262144) {               // WoT: 256 x 256
        int loc = id - 196608; int n = loc >> 8, k = loc & 255;
        WoT[n * 256 + k] = (__bf16)Wo[k * 256 + n];
    } else if (id < 524288) {               // W1T: 1024 x 256
        int loc = id - 262144; int n = loc >> 8, k = loc & 255;
        W1T[n * 256 + k] = (__bf16)W1[k * 1024 + n];
    } else if (id < 786432) {               // W2T: 256 x 1024
        int loc = id - 524288; int n = loc >> 10, k = loc & 1023;
        W2T[n * 1024 + k] = (__bf16)W2[k * 256 + n];
    } else if (id < 787200) {               // bqkv: 768
        int i = id - 786432;
        bqkv[i] = (i < 256) ? bq[i] : (i < 512) ? bk[i - 256] : bv[i - 512];
    }
}

// ---------------- generic MFMA GEMM: out[M,N] = A[M,K] @ Bt[N,K]^T + bias ---
// EPI: 0 = f32 store, 1 = bf16 store, 2 = gelu -> bf16 store
template <typename TA, int EPI>
__global__ __launch_bounds__(256) void gemm_kernel(
    const TA* __restrict__ A, const __bf16* __restrict__ Bt,
    const float* __restrict__ bias, void* __restrict__ outp,
    int M, int N, int K)
{
    __shared__ __bf16 As[128][40];   // +8 pad: 2-way bank alias only (free)
    __shared__ __bf16 Bs[128][40];
    const int t = threadIdx.x;
    const int w = t >> 6, l = t & 63;
    const int wr = w >> 1, wc = w & 1;        // wave -> 64x64 quadrant
    const int lr = l & 15, lg = l >> 4;
    const int bm = blockIdx.y * 128, bn = blockIdx.x * 128;
    const int srow = t >> 1, sc0 = (t & 1) * 16;

    f32x4 acc[4][4];
#pragma unroll
    for (int m = 0; m < 4; m++)
#pragma unroll
        for (int n = 0; n < 4; n++) acc[m][n] = (f32x4){0.f, 0.f, 0.f, 0.f};

    for (int k0 = 0; k0 < K; k0 += 32) {
        // stage A (fp32 converts on the fly; bf16 copies 16B vectors)
        if constexpr (std::is_same<TA, float>::value) {
            const float* ap = A + (size_t)(bm + srow) * K + k0 + sc0;
            __bf16 tmp[16];
#pragma unroll
            for (int i = 0; i < 16; i += 4) {
                float4 f = *(const float4*)(ap + i);
                tmp[i] = (__bf16)f.x; tmp[i + 1] = (__bf16)f.y;
                tmp[i + 2] = (__bf16)f.z; tmp[i + 3] = (__bf16)f.w;
            }
            *(bf16x8*)&As[srow][sc0]     = *(bf16x8*)&tmp[0];
            *(bf16x8*)&As[srow][sc0 + 8] = *(bf16x8*)&tmp[8];
        } else {
            const __bf16* ap = A + (size_t)(bm + srow) * K + k0 + sc0;
            *(bf16x8*)&As[srow][sc0]     = *(const bf16x8*)(ap);
            *(bf16x8*)&As[srow][sc0 + 8] = *(const bf16x8*)(ap + 8);
        }
        {
            const __bf16* bp = Bt + (size_t)(bn + srow) * K + k0 + sc0;
            *(bf16x8*)&Bs[srow][sc0]     = *(const bf16x8*)(bp);
            *(bf16x8*)&Bs[srow][sc0 + 8] = *(const bf16x8*)(bp + 8);
        }
        __syncthreads();
        bf16x8 af[4], bfr[4];
#pragma unroll
        for (int m = 0; m < 4; m++)
            af[m] = *(bf16x8*)&As[wr * 64 + m * 16 + lr][lg * 8];
#pragma unroll
        for (int n = 0; n < 4; n++)
            bfr[n] = *(bf16x8*)&Bs[wc * 64 + n * 16 + lr][lg * 8];
#pragma unroll
        for (int m = 0; m < 4; m++)
#pragma unroll
            for (int n = 0; n < 4; n++)
                acc[m][n] = __builtin_amdgcn_mfma_f32_16x16x32_bf16(
                    af[m], bfr[n], acc[m][n], 0, 0, 0);
        __syncthreads();
    }

#pragma unroll
    for (int n = 0; n < 4; n++) {
        const int col = bn + wc * 64 + n * 16 + lr;
        const float bv = bias[col];
#pragma unroll
        for (int m = 0; m < 4; m++) {
#pragma unroll
            for (int r = 0; r < 4; r++) {
                const int row = bm + wr * 64 + m * 16 + lg * 4 + r;
                float v = acc[m][n][r] + bv;
                if constexpr (EPI == 0)
                    ((float*)outp)[(size_t)row * N + col] = v;
                else if constexpr (EPI == 1)
                    ((__bf16*)outp)[(size_t)row * N + col] = (__bf16)v;
                else
                    ((__bf16*)outp)[(size_t)row * N + col] = (__bf16)gelu_tanh(v);
            }
        }
    }
}

// ---------------- fused attention per (b,h) --------------------------------
__global__ __launch_bounds__(256) void attn_kernel(
    const __bf16* __restrict__ QKVb,   // (B*N) x 768 [Q|K|V]
    const float* __restrict__ adj, const float* __restrict__ dist,
    const float* __restrict__ mask,
    float* __restrict__ attn_out,      // B*H*N*N
    __bf16* __restrict__ ctx)          // (B*N) x 256
{
    __shared__ __bf16 Qs[128][40], Ks[128][40];
    __shared__ __bf16 Vt[32][136];     // V transposed [d][k]
    __shared__ __bf16 Ps[128][136];    // softmax probs (bf16) for PV
    const int bh = blockIdx.x, b = bh >> 3, h = bh & 7;
    const int t = threadIdx.x;
    const int w = t >> 6, l = t & 63;
    const int lr = l & 15, lg = l >> 4;
    {
        const int n = t >> 1, half = t & 1;
        const __bf16* base = QKVb + (size_t)(b * 128 + n) * 768 + h * 32 + half * 16;
        *(bf16x8*)&Qs[n][half * 16]     = *(const bf16x8*)(base);
        *(bf16x8*)&Qs[n][half * 16 + 8] = *(const bf16x8*)(base + 8);
        *(bf16x8*)&Ks[n][half * 16]     = *(const bf16x8*)(base + 256);
        *(bf16x8*)&Ks[n][half * 16 + 8] = *(const bf16x8*)(base + 256 + 8);
        bf16x8 v0 = *(const bf16x8*)(base + 512);
        bf16x8 v1 = *(const bf16x8*)(base + 512 + 8);
#pragma unroll
        for (int i = 0; i < 8; i++) Vt[half * 16 + i][n] = v0[i];
#pragma unroll
        for (int i = 0; i < 8; i++) Vt[half * 16 + 8 + i][n] = v1[i];
    }
    __syncthreads();

    // scores: wave w owns query rows [w*32, w*32+32)
    f32x4 s[2][8];
    bf16x8 aq[2];
#pragma unroll
    for (int mt = 0; mt < 2; mt++)
        aq[mt] = *(bf16x8*)&Qs[w * 32 + mt * 16 + lr][lg * 8];
#pragma unroll
    for (int nt = 0; nt < 8; nt++) {
        bf16x8 bk_ = *(bf16x8*)&Ks[nt * 16 + lr][lg * 8];
#pragma unroll
        for (int mt = 0; mt < 2; mt++)
            s[mt][nt] = __builtin_amdgcn_mfma_f32_16x16x32_bf16(
                aq[mt], bk_, (f32x4){0.f, 0.f, 0.f, 0.f}, 0, 0, 0);
    }
    const float scale = 0.17677669529663687f;  // 1/sqrt(32)
    const float* adjb  = adj  + (size_t)b * 16384;
    const float* distb = dist + (size_t)b * 16384;
    float ma[8];
#pragma unroll
    for (int nt = 0; nt < 8; nt++)
        ma[nt] = (1.0f - mask[b * 128 + nt * 16 + lr]) * -1e9f;
#pragma unroll
    for (int mt = 0; mt < 2; mt++)
#pragma unroll
        for (int nt = 0; nt < 8; nt++)
#pragma unroll
            for (int r = 0; r < 4; r++) {
                int i = w * 32 + mt * 16 + lg * 4 + r, j = nt * 16 + lr;
                s[mt][nt][r] = s[mt][nt][r] * scale + adjb[i * 128 + j] +
                               distb[i * 128 + j] + ma[nt];
            }
    // softmax along j (row i spans 8 nt regs x 16 lanes of this lane-group)
    float* attn_base = attn_out + (size_t)bh * 16384;
#pragma unroll
    for (int mt = 0; mt < 2; mt++) {
#pragma unroll
        for (int r = 0; r < 4; r++) {
            float mx = s[mt][0][r];
#pragma unroll
            for (int nt = 1; nt < 8; nt++) mx = fmaxf(mx, s[mt][nt][r]);
#pragma unroll
            for (int msk = 1; msk < 16; msk <<= 1)
                mx = fmaxf(mx, __shfl_xor(mx, msk, 64));
            float p[8], sum = 0.f;
#pragma unroll
            for (int nt = 0; nt < 8; nt++) {
                p[nt] = __expf(s[mt][nt][r] - mx);
                sum += p[nt];
            }
#pragma unroll
            for (int msk = 1; msk < 16; msk <<= 1)
                sum += __shfl_xor(sum, msk, 64);
            float rinv = 1.0f / sum;
            int i = w * 32 + mt * 16 + lg * 4 + r;
#pragma unroll
            for (int nt = 0; nt < 8; nt++) {
                float a_ = p[nt] * rinv;
                attn_base[(size_t)i * 128 + nt * 16 + lr] = a_;
                Ps[i][nt * 16 + lr] = (__bf16)a_;
            }
        }
    }
    __syncthreads();
    // PV: (128x128) @ (128x32)
    f32x4 c[2][2];
#pragma unroll
    for (int mt = 0; mt < 2; mt++)
#pragma unroll
        for (int n2 = 0; n2 < 2; n2++) c[mt][n2] = (f32x4){0.f, 0.f, 0.f, 0.f};
#pragma unroll
    for (int ks = 0; ks < 4; ks++) {
        bf16x8 ap[2], bv_[2];
#pragma unroll
        for (int mt = 0; mt < 2; mt++)
            ap[mt] = *(bf16x8*)&Ps[w * 32 + mt * 16 + lr][ks * 32 + lg * 8];
#pragma unroll
        for (int n2 = 0; n2 < 2; n2++)
            bv_[n2] = *(bf16x8*)&Vt[n2 * 16 + lr][ks * 32 + lg * 8];
#pragma unroll
        for (int mt = 0; mt < 2; mt++)
#pragma unroll
            for (int n2 = 0; n2 < 2; n2++)
                c[mt][n2] = __builtin_amdgcn_mfma_f32_16x16x32_bf16(
                    ap[mt], bv_[n2], c[mt][n2], 0, 0, 0);
    }
#pragma unroll
    for (int mt = 0; mt < 2; mt++)
#pragma unroll
        for (int n2 = 0; n2 < 2; n2++)
#pragma unroll
            for (int r = 0; r < 4; r++) {
                int i = w * 32 + mt * 16 + lg * 4 + r, d = n2 * 16 + lr;
                ctx[(size_t)(b * 128 + i) * 256 + h * 32 + d] = (__bf16)c[mt][n2][r];
            }
}

// ---------------- AddNorm: out = X + LN(Y)*g + b (wave per row of 256) -----
__global__ __launch_bounds__(256) void addnorm_kernel(
    const float* __restrict__ X, const float* __restrict__ Y,
    const float* __restrict__ g, const float* __restrict__ be,
    float* __restrict__ out)
{
    const int w = threadIdx.x >> 6, l = threadIdx.x & 63;
    const size_t row = (size_t)blockIdx.x * 4 + w;
    const float4 y = *(const float4*)&Y[row * 256 + l * 4];
    float s = y.x + y.y + y.z + y.w;
    float q = y.x * y.x + y.y * y.y + y.z * y.z + y.w * y.w;
#pragma unroll
    for (int m = 1; m < 64; m <<= 1) {
        s += __shfl_xor(s, m, 64);
        q += __shfl_xor(q, m, 64);
    }
    const float mean = s * (1.f / 256.f);
    const float rs = rsqrtf(q * (1.f / 256.f) - mean * mean + 1e-5f);
    const float4 x = *(const float4*)&X[row * 256 + l * 4];
    const float4 gg = *(const float4*)&g[l * 4];
    const float4 bb = *(const float4*)&be[l * 4];
    float4 o;
    o.x = x.x + (y.x - mean) * rs * gg.x + bb.x;
    o.y = x.y + (y.y - mean) * rs * gg.y + bb.y;
    o.z = x.z + (y.z - mean) * rs * gg.z + bb.z;
    o.w = x.w + (y.w - mean) * rs * gg.w + bb.w;
    *(float4*)&out[row * 256 + l * 4] = o;
}

// ---------------------------------------------------------------------------
extern "C" void kernel_launch(void* const* d_in, const int* in_sizes, int n_in,
                              void* d_out, int out_size, void* d_ws, size_t ws_size,
                              hipStream_t stream)
{
    const float* node_emb  = (const float*)d_in[0];
    const float* node_mask = (const float*)d_in[1];
    const float* adjacency = (const float*)d_in[2];
    const float* distance  = (const float*)d_in[3];
    const float* Wq = (const float*)d_in[4];
    const float* bq = (const float*)d_in[5];
    const float* Wk = (const float*)d_in[6];
    const float* bk = (const float*)d_in[7];
    const float* Wv = (const float*)d_in[8];
    const float* bv = (const float*)d_in[9];
    const float* Wo = (const float*)d_in[10];
    const float* bo = (const float*)d_in[11];
    const float* ln1g = (const float*)d_in[12];
    const float* ln1b = (const float*)d_in[13];
    const float* W1 = (const float*)d_in[14];
    const float* b1 = (const float*)d_in[15];
    const float* W2 = (const float*)d_in[16];
    const float* b2 = (const float*)d_in[17];
    const float* ln2g = (const float*)d_in[18];
    const float* ln2b = (const float*)d_in[19];

    char* ws = (char*)d_ws;
    __bf16* WqkvT = (__bf16*)(ws + 0);          //   768*256*2 = 393216
    __bf16* WoT   = (__bf16*)(ws + 393216);     //   256*256*2 = 131072
    __bf16* W1T   = (__bf16*)(ws + 524288);     //  1024*256*2 = 524288
    __bf16* W2T   = (__bf16*)(ws + 1048576);    //  256*1024*2 = 524288
    float*  bqkv  = (float*)(ws + 1572864);     //   768*4     = 3072
    __bf16* QKVb  = (__bf16*)(ws + 1575936);    // 32768*768*2 = 48M
    __bf16* ctx   = (__bf16*)(ws + 51907584);   // 32768*256*2 = 16M
    float*  Yb    = (float*)(ws + 68684800);    // 32768*256*4 = 32M
    float*  X1    = (float*)(ws + 102239232);   // 32768*256*4 = 32M
    __bf16* Hb    = (__bf16*)(ws + 135793664);  // 32768*1024*2= 64M -> end ~193.5M
    float*  Y2    = (float*)QKVb;               // reuse (dead after attention)

    float* Xout = (float*)d_out;
    float* attn_out = Xout + (size_t)256 * 128 * 256;  // 8388608

    prep_kernel<<<3075, 256, 0, stream>>>(Wq, Wk, Wv, Wo, W1, W2, bq, bk, bv,
                                          WqkvT, WoT, W1T, W2T, bqkv);
    // QKV = X @ [Wq|Wk|Wv] + b  -> bf16
    gemm_kernel<float, 1><<<dim3(6, 256), 256, 0, stream>>>(
        node_emb, WqkvT, bqkv, QKVb, 32768, 768, 256);
    // attention (writes attn f32 to d_out, ctx bf16 to ws)
    attn_kernel<<<2048, 256, 0, stream>>>(QKVb, adjacency, distance, node_mask,
                                          attn_out, ctx);
    // Y = ctx @ Wo + bo
    gemm_kernel<__bf16, 0><<<dim3(2, 256), 256, 0, stream>>>(
        ctx, WoT, bo, Yb, 32768, 256, 256);
    // X1 = X + LN(Y)
    addnorm_kernel<<<8192, 256, 0, stream>>>(node_emb, Yb, ln1g, ln1b, X1);
    // H = gelu(X1 @ W1 + b1) -> bf16
    gemm_kernel<float, 2><<<dim3(8, 256), 256, 0, stream>>>(
        X1, W1T, b1, Hb, 32768, 1024, 256);
    // Y2 = H @ W2 + b2
    gemm_kernel<__bf16, 0><<<dim3(2, 256), 256, 0, stream>>>(
        Hb, W2T, b2, Y2, 32768, 256, 1024);
    // out X = X1 + LN(Y2)
    addnorm_kernel<<<8192, 256, 0, stream>>>(X1, Y2, ln2g, ln2b, Xout);
}

// Round 3
// 503.143 us; speedup vs baseline: 1.0090x; 1.0090x over previous
//
#include <hip/hip_runtime.h>
#include <hip/hip_bf16.h>

// GTMGC block: B=256, N=128, D=256, H=8, hd=32, FFN=1024
// out = [X (B*N*D f32) | attn (B*H*N*N f32)]

typedef __bf16 bf16x8 __attribute__((ext_vector_type(8)));
typedef __bf16 bf16x4 __attribute__((ext_vector_type(4)));
typedef float f32x4 __attribute__((ext_vector_type(4)));

__device__ __forceinline__ float gelu_tanh(float x) {
    // jax.nn.gelu approximate=True
    float x3 = x * x * x;
    float t = tanhf(0.7978845608028654f * (x + 0.044715f * x3));
    return 0.5f * x * (1.0f + t);
}

// ---------------- prep: weights -> bf16 [N][K], qkv bias concat, X -> bf16 --
__global__ __launch_bounds__(256) void prep_kernel(
    const float* __restrict__ Wq, const float* __restrict__ Wk,
    const float* __restrict__ Wv, const float* __restrict__ Wo,
    const float* __restrict__ W1, const float* __restrict__ W2,
    const float* __restrict__ bq, const float* __restrict__ bk,
    const float* __restrict__ bv, const float* __restrict__ X0,
    __bf16* __restrict__ WqkvT, __bf16* __restrict__ WoT,
    __bf16* __restrict__ W1T, __bf16* __restrict__ W2T,
    float* __restrict__ bqkv, __bf16* __restrict__ X0b)
{
    int id = blockIdx.x * 256 + threadIdx.x;
    if (id < 196608) {                      // WqkvT: 768 x 256
        int n = id >> 8, k = id & 255;
        float v = (n < 256) ? Wq[k * 256 + n]
                : (n < 512) ? Wk[k * 256 + (n - 256)]
                            : Wv[k * 256 + (n - 512)];
        WqkvT[n * 256 + k] = (__bf16)v;
    } else if (id < 262144) {               // WoT: 256 x 256
        int loc = id - 196608; int n = loc >> 8, k = loc & 255;
        WoT[n * 256 + k] = (__bf16)Wo[k * 256 + n];
    } else if (id < 524288) {               // W1T: 1024 x 256
        int loc = id - 262144; int n = loc >> 8, k = loc & 255;
        W1T[n * 256 + k] = (__bf16)W1[k * 1024 + n];
    } else if (id < 786432) {               // W2T: 256 x 1024
        int loc = id - 524288; int n = loc >> 10, k = loc & 1023;
        W2T[n * 1024 + k] = (__bf16)W2[k * 256 + n];
    } else if (id < 787200) {               // bqkv: 768
        int i = id - 786432;
        bqkv[i] = (i < 256) ? bq[i] : (i < 512) ? bk[i - 256] : bv[i - 512];
    } else {                                // X0b: 32768*256 bf16
        int i = id - 787200;
        X0b[i] = (__bf16)X0[i];
    }
}

// ------- MFMA GEMM, 128x256 tile: out[M,N] = A[M,K] @ Bt[N,K]^T + bias -----
// EPI: 0 = f32 store, 1 = bf16 store, 2 = gelu -> bf16 store
template <int EPI>
__global__ __launch_bounds__(256, 2) void gemm_kernel(
    const __bf16* __restrict__ A, const __bf16* __restrict__ Bt,
    const float* __restrict__ bias, void* __restrict__ outp,
    int M, int N, int K)
{
    __shared__ __bf16 As[128][40];   // +8 pad: 2-way bank alias only (free)
    __shared__ __bf16 Bs[256][40];
    const int t = threadIdx.x;
    const int w = t >> 6, l = t & 63;
    const int wr = w >> 1, wc = w & 1;        // wave -> 64x128 sub-tile
    const int lr = l & 15, lg = l >> 4;
    const int bm = blockIdx.y * 128, bn = blockIdx.x * 256;
    const int arow = t >> 1, ac0 = (t & 1) * 16;

    f32x4 acc[4][8];
#pragma unroll
    for (int m = 0; m < 4; m++)
#pragma unroll
        for (int n = 0; n < 8; n++) acc[m][n] = (f32x4){0.f, 0.f, 0.f, 0.f};

    for (int k0 = 0; k0 < K; k0 += 32) {
        {
            const __bf16* ap = A + (size_t)(bm + arow) * K + k0 + ac0;
            *(bf16x8*)&As[arow][ac0]     = *(const bf16x8*)(ap);
            *(bf16x8*)&As[arow][ac0 + 8] = *(const bf16x8*)(ap + 8);
        }
        {
            const __bf16* bp = Bt + (size_t)(bn + t) * K + k0;
            *(bf16x8*)&Bs[t][0]  = *(const bf16x8*)(bp);
            *(bf16x8*)&Bs[t][8]  = *(const bf16x8*)(bp + 8);
            *(bf16x8*)&Bs[t][16] = *(const bf16x8*)(bp + 16);
            *(bf16x8*)&Bs[t][24] = *(const bf16x8*)(bp + 24);
        }
        __syncthreads();
        bf16x8 af[4], bf_[8];
#pragma unroll
        for (int m = 0; m < 4; m++)
            af[m] = *(bf16x8*)&As[wr * 64 + m * 16 + lr][lg * 8];
#pragma unroll
        for (int n = 0; n < 8; n++)
            bf_[n] = *(bf16x8*)&Bs[wc * 128 + n * 16 + lr][lg * 8];
#pragma unroll
        for (int m = 0; m < 4; m++)
#pragma unroll
            for (int n = 0; n < 8; n++)
                acc[m][n] = __builtin_amdgcn_mfma_f32_16x16x32_bf16(
                    af[m], bf_[n], acc[m][n], 0, 0, 0);
        __syncthreads();
    }

#pragma unroll
    for (int n = 0; n < 8; n++) {
        const int col = bn + wc * 128 + n * 16 + lr;
        const float bv = bias[col];
#pragma unroll
        for (int m = 0; m < 4; m++) {
#pragma unroll
            for (int r = 0; r < 4; r++) {
                const int row = bm + wr * 64 + m * 16 + lg * 4 + r;
                float v = acc[m][n][r] + bv;
                if constexpr (EPI == 0)
                    ((float*)outp)[(size_t)row * N + col] = v;
                else if constexpr (EPI == 1)
                    ((__bf16*)outp)[(size_t)row * N + col] = (__bf16)v;
                else
                    ((__bf16*)outp)[(size_t)row * N + col] = (__bf16)gelu_tanh(v);
            }
        }
    }
}

// ---------------- fused attention: one block per molecule b, loop heads ----
__global__ __launch_bounds__(512) void attn_kernel(
    const __bf16* __restrict__ QKVb,   // (B*N) x 768 [Q|K|V]
    const float* __restrict__ adj, const float* __restrict__ dist,
    const float* __restrict__ mask,
    float* __restrict__ attn_out,      // B*H*N*N
    __bf16* __restrict__ ctx)          // (B*N) x 256
{
    __shared__ __bf16 Qs[128][40], Ks[128][40];
    __shared__ __bf16 Vt[32][136];     // V transposed [d][k]
    __shared__ __bf16 Ps[128][136];    // softmax probs (bf16) for PV
    const int b = blockIdx.x;
    const int t = threadIdx.x;
    const int w = t >> 6, l = t & 63;  // 8 waves; wave w owns rows w*16..+16
    const int lr = l & 15, lg = l >> 4;

    // bias = adj + dist + key-mask, held in registers across all 8 heads
    const float* adjb  = adj  + (size_t)b * 16384;
    const float* distb = dist + (size_t)b * 16384;
    float breg[8][4];
#pragma unroll
    for (int nt = 0; nt < 8; nt++) {
        const int j = nt * 16 + lr;
        const float madd = (1.0f - mask[b * 128 + j]) * -1e9f;
#pragma unroll
        for (int r = 0; r < 4; r++) {
            const int i = w * 16 + lg * 4 + r;
            breg[nt][r] = adjb[i * 128 + j] + distb[i * 128 + j] + madd;
        }
    }

    const int srow = t >> 2, sq = (t & 3) * 8;
    const __bf16* qkvrow = QKVb + (size_t)(b * 128 + srow) * 768 + sq;
    const float scale = 0.17677669529663687f;  // 1/sqrt(32)

    for (int h = 0; h < 8; h++) {
        // stage Q,K (row-major) and V (transposed) for head h
        *(bf16x8*)&Qs[srow][sq] = *(const bf16x8*)(qkvrow + h * 32);
        *(bf16x8*)&Ks[srow][sq] = *(const bf16x8*)(qkvrow + h * 32 + 256);
        bf16x8 v8 = *(const bf16x8*)(qkvrow + h * 32 + 512);
#pragma unroll
        for (int i2 = 0; i2 < 8; i2++) Vt[sq + i2][srow] = v8[i2];
        __syncthreads();

        // scores for 16 query rows per wave
        bf16x8 aq = *(bf16x8*)&Qs[w * 16 + lr][lg * 8];
        f32x4 s[8];
#pragma unroll
        for (int nt = 0; nt < 8; nt++) {
            bf16x8 bk_ = *(bf16x8*)&Ks[nt * 16 + lr][lg * 8];
            s[nt] = __builtin_amdgcn_mfma_f32_16x16x32_bf16(
                aq, bk_, (f32x4){0.f, 0.f, 0.f, 0.f}, 0, 0, 0);
        }
#pragma unroll
        for (int nt = 0; nt < 8; nt++)
#pragma unroll
            for (int r = 0; r < 4; r++)
                s[nt][r] = s[nt][r] * scale + breg[nt][r];

        // softmax along j; write attn f32 + Ps bf16
        float* attn_base = attn_out + (size_t)(b * 8 + h) * 16384;
#pragma unroll
        for (int r = 0; r < 4; r++) {
            float mx = s[0][r];
#pragma unroll
            for (int nt = 1; nt < 8; nt++) mx = fmaxf(mx, s[nt][r]);
#pragma unroll
            for (int msk = 1; msk < 16; msk <<= 1)
                mx = fmaxf(mx, __shfl_xor(mx, msk, 64));
            float p[8], sum = 0.f;
#pragma unroll
            for (int nt = 0; nt < 8; nt++) {
                p[nt] = __expf(s[nt][r] - mx);
                sum += p[nt];
            }
#pragma unroll
            for (int msk = 1; msk < 16; msk <<= 1)
                sum += __shfl_xor(sum, msk, 64);
            const float rinv = 1.0f / sum;
            const int i = w * 16 + lg * 4 + r;
#pragma unroll
            for (int nt = 0; nt < 8; nt++) {
                float a_ = p[nt] * rinv;
                attn_base[(size_t)i * 128 + nt * 16 + lr] = a_;
                Ps[i][nt * 16 + lr] = (__bf16)a_;
            }
        }
        __syncthreads();

        // PV: (128x128) @ (128x32); per wave 16 rows x 32 d
        f32x4 c[2];
        c[0] = (f32x4){0.f, 0.f, 0.f, 0.f};
        c[1] = (f32x4){0.f, 0.f, 0.f, 0.f};
#pragma unroll
        for (int ks = 0; ks < 4; ks++) {
            bf16x8 ap = *(bf16x8*)&Ps[w * 16 + lr][ks * 32 + lg * 8];
#pragma unroll
            for (int n2 = 0; n2 < 2; n2++) {
                bf16x8 bv_ = *(bf16x8*)&Vt[n2 * 16 + lr][ks * 32 + lg * 8];
                c[n2] = __builtin_amdgcn_mfma_f32_16x16x32_bf16(
                    ap, bv_, c[n2], 0, 0, 0);
            }
        }
#pragma unroll
        for (int n2 = 0; n2 < 2; n2++)
#pragma unroll
            for (int r = 0; r < 4; r++) {
                const int i = w * 16 + lg * 4 + r, d = n2 * 16 + lr;
                ctx[(size_t)(b * 128 + i) * 256 + h * 32 + d] = (__bf16)c[n2][r];
            }
        __syncthreads();   // protect Qs/Ks/Vt/Ps before next head's staging
    }
}

// --------- AddNorm: out = X + LN(Y)*g + b (wave per row of 256) ------------
template <bool WRITE_BF16>
__global__ __launch_bounds__(256) void addnorm_kernel(
    const float* __restrict__ X, const float* __restrict__ Y,
    const float* __restrict__ g, const float* __restrict__ be,
    float* __restrict__ out, __bf16* __restrict__ outb)
{
    const int w = threadIdx.x >> 6, l = threadIdx.x & 63;
    const size_t row = (size_t)blockIdx.x * 4 + w;
    const float4 y = *(const float4*)&Y[row * 256 + l * 4];
    float s = y.x + y.y + y.z + y.w;
    float q = y.x * y.x + y.y * y.y + y.z * y.z + y.w * y.w;
#pragma unroll
    for (int m = 1; m < 64; m <<= 1) {
        s += __shfl_xor(s, m, 64);
        q += __shfl_xor(q, m, 64);
    }
    const float mean = s * (1.f / 256.f);
    const float rs = rsqrtf(q * (1.f / 256.f) - mean * mean + 1e-5f);
    const float4 x = *(const float4*)&X[row * 256 + l * 4];
    const float4 gg = *(const float4*)&g[l * 4];
    const float4 bb = *(const float4*)&be[l * 4];
    float4 o;
    o.x = x.x + (y.x - mean) * rs * gg.x + bb.x;
    o.y = x.y + (y.y - mean) * rs * gg.y + bb.y;
    o.z = x.z + (y.z - mean) * rs * gg.z + bb.z;
    o.w = x.w + (y.w - mean) * rs * gg.w + bb.w;
    *(float4*)&out[row * 256 + l * 4] = o;
    if constexpr (WRITE_BF16) {
        bf16x4 ob;
        ob[0] = (__bf16)o.x; ob[1] = (__bf16)o.y;
        ob[2] = (__bf16)o.z; ob[3] = (__bf16)o.w;
        *(bf16x4*)&outb[row * 256 + l * 4] = ob;
    }
}

// ---------------------------------------------------------------------------
extern "C" void kernel_launch(void* const* d_in, const int* in_sizes, int n_in,
                              void* d_out, int out_size, void* d_ws, size_t ws_size,
                              hipStream_t stream)
{
    const float* node_emb  = (const float*)d_in[0];
    const float* node_mask = (const float*)d_in[1];
    const float* adjacency = (const float*)d_in[2];
    const float* distance  = (const float*)d_in[3];
    const float* Wq = (const float*)d_in[4];
    const float* bq = (const float*)d_in[5];
    const float* Wk = (const float*)d_in[6];
    const float* bk = (const float*)d_in[7];
    const float* Wv = (const float*)d_in[8];
    const float* bv = (const float*)d_in[9];
    const float* Wo = (const float*)d_in[10];
    const float* bo = (const float*)d_in[11];
    const float* ln1g = (const float*)d_in[12];
    const float* ln1b = (const float*)d_in[13];
    const float* W1 = (const float*)d_in[14];
    const float* b1 = (const float*)d_in[15];
    const float* W2 = (const float*)d_in[16];
    const float* b2 = (const float*)d_in[17];
    const float* ln2g = (const float*)d_in[18];
    const float* ln2b = (const float*)d_in[19];

    char* ws = (char*)d_ws;
    __bf16* WqkvT = (__bf16*)(ws + 0);           //   768*256*2 = 393216
    __bf16* WoT   = (__bf16*)(ws + 393216);      //   256*256*2 = 131072
    __bf16* W1T   = (__bf16*)(ws + 524288);      //  1024*256*2 = 524288
    __bf16* W2T   = (__bf16*)(ws + 1048576);     //  256*1024*2 = 524288
    float*  bqkv  = (float*)(ws + 1572864);      //   768*4     = 3072
    __bf16* X0b   = (__bf16*)(ws + 1575936);     // 32768*256*2 = 16777216
    __bf16* QKVb  = (__bf16*)(ws + 18353152);    // 32768*768*2 = 50331648
    __bf16* ctx   = (__bf16*)(ws + 68684800);    // 32768*256*2 = 16777216
    float*  Yb    = (float*)(ws + 85462016);     // 32768*256*4 = 33554432
    float*  X1    = (float*)(ws + 119016448);    // 32768*256*4 = 33554432
    __bf16* X1b   = (__bf16*)(ws + 152570880);   // 32768*256*2 = 16777216
    __bf16* Hb    = (__bf16*)(ws + 169348096);   // 32768*1024*2= 67108864 -> ~236.5M
    float*  Y2    = (float*)QKVb;                // reuse (dead after attention)

    float* Xout = (float*)d_out;
    float* attn_out = Xout + (size_t)256 * 128 * 256;  // 8388608

    prep_kernel<<<35843, 256, 0, stream>>>(Wq, Wk, Wv, Wo, W1, W2, bq, bk, bv,
                                           node_emb, WqkvT, WoT, W1T, W2T,
                                           bqkv, X0b);
    // QKV = X @ [Wq|Wk|Wv] + b  -> bf16
    gemm_kernel<1><<<dim3(3, 256), 256, 0, stream>>>(
        X0b, WqkvT, bqkv, QKVb, 32768, 768, 256);
    // attention: one block per b, 8 heads looped (writes attn f32 + ctx bf16)
    attn_kernel<<<256, 512, 0, stream>>>(QKVb, adjacency, distance, node_mask,
                                         attn_out, ctx);
    // Y = ctx @ Wo + bo
    gemm_kernel<0><<<dim3(1, 256), 256, 0, stream>>>(
        ctx, WoT, bo, Yb, 32768, 256, 256);
    // X1 = X + LN(Y)   (+ bf16 copy for FFN input)
    addnorm_kernel<true><<<8192, 256, 0, stream>>>(node_emb, Yb, ln1g, ln1b,
                                                   X1, X1b);
    // H = gelu(X1 @ W1 + b1) -> bf16   (N=1024 -> 4 tiles of 256)
    gemm_kernel<2><<<dim3(4, 256), 256, 0, stream>>>(
        X1b, W1T, b1, Hb, 32768, 1024, 256);
    // Y2 = H @ W2 + b2
    gemm_kernel<0><<<dim3(1, 256), 256, 0, stream>>>(
        Hb, W2T, b2, Y2, 32768, 256, 1024);
    // out X = X1 + LN(Y2)
    addnorm_kernel<false><<<8192, 256, 0, stream>>>(X1, Y2, ln2g, ln2b,
                                                    Xout, nullptr);
}